// Round 7
// baseline (276.269 us; speedup 1.0000x reference)
//
#include <hip/hip_runtime.h>
#include <hip/hip_bf16.h>
#include <math.h>

typedef __hip_bfloat16 bf16;
typedef __attribute__((ext_vector_type(8))) short short8;
typedef __attribute__((ext_vector_type(4))) float f32x4;

#define NB 2
#define HH 96
#define WW 96
#define CC 256
#define NHEADS 8
#define PP 25
#define DHH 32
#define HIDN 1024
#define LQ (HH*WW)          // 9216
#define TT (NB*LQ)          // 18432
#define NVC 896             // 256 val + 400 off + 200 attn + 40 pad
#define TB 8                // tokens per sample block

__device__ __forceinline__ float b2f(bf16 v){ return __bfloat162float(v); }
__device__ __forceinline__ bf16  f2b(float v){ return __float2bfloat16(v); }
__device__ __forceinline__ float lo_bf(unsigned u){ return __uint_as_float(u << 16); }
__device__ __forceinline__ float hi_bf(unsigned u){ return __uint_as_float(u & 0xffff0000u); }

__device__ __forceinline__ void gl2lds16(const void* g, void* l) {
    __builtin_amdgcn_global_load_lds(
        (const __attribute__((address_space(1))) unsigned int*)g,
        (__attribute__((address_space(3))) unsigned int*)l, 16, 0, 0);
}

// ---------------- all weight prep in one kernel ---------------------------------
__global__ __launch_bounds__(256) void prep_all(const float* __restrict__ w_val,
                                                const float* __restrict__ w_off,
                                                const float* __restrict__ w_attn,
                                                const float* __restrict__ w_fc1,
                                                const float* __restrict__ w_fc2,
                                                const float* __restrict__ w_out,
                                                const float* __restrict__ b_val,
                                                const float* __restrict__ b_off,
                                                const float* __restrict__ b_attn,
                                                bf16* __restrict__ wvcT,
                                                bf16* __restrict__ wfc1T,
                                                bf16* __restrict__ wfc2T,
                                                bf16* __restrict__ woutT,
                                                float* __restrict__ bvc)
{
    const int idx = blockIdx.x*256 + threadIdx.x;   // < 819200
    if (idx < 229376) {                              // wvcT [896][256]
        int n = idx >> 8, k = idx & 255;
        float v = (n < 256) ? w_val[(size_t)k*256 + n]
                : (n < 656) ? w_off[(size_t)k*400 + (n-256)]
                : (n < 856) ? w_attn[(size_t)k*200 + (n-656)] : 0.f;
        wvcT[idx] = f2b(v);
    } else if (idx < 491520) {                       // wfc1T [1024][256]
        int j = idx - 229376; int n = j >> 8, k = j & 255;
        wfc1T[j] = f2b(w_fc1[(size_t)k*1024 + n]);
    } else if (idx < 753664) {                       // wfc2T [256][1024]
        int j = idx - 491520; int n = j >> 10, k = j & 1023;
        wfc2T[j] = f2b(w_fc2[(size_t)k*256 + n]);
    } else if (idx < 819200) {                       // woutT [256][256]
        int j = idx - 753664; int n = j >> 8, k = j & 255;
        woutT[j] = f2b(w_out[(size_t)k*256 + n]);
    }
    if (idx < NVC)
        bvc[idx] = (idx < 256) ? b_val[idx]
                 : (idx < 656) ? b_off[idx-256]
                 : (idx < 856) ? b_attn[idx-656] : 0.f;
}

// ---------------- LayerNorm: one wave per token, 4 ch/lane ----------------------
__global__ __launch_bounds__(256) void ln_kernel(const float* __restrict__ x,
                                                 const float* __restrict__ g,
                                                 const float* __restrict__ b,
                                                 bf16* __restrict__ out)
{
    const int t = blockIdx.x*4 + (threadIdx.x >> 6);
    const int l = threadIdx.x & 63;
    const float4 v = *(const float4*)(x + (size_t)t*CC + l*4);
    float s  = v.x + v.y + v.z + v.w;
    float s2 = v.x*v.x + v.y*v.y + v.z*v.z + v.w*v.w;
    #pragma unroll
    for (int m = 1; m < 64; m <<= 1) { s += __shfl_xor(s, m); s2 += __shfl_xor(s2, m); }
    const float mean = s * (1.f/CC);
    const float var  = s2 * (1.f/CC) - mean*mean;
    const float rs   = 1.f / sqrtf(var + 1e-5f);
    const float4 gg = *(const float4*)(g + l*4);
    const float4 bb = *(const float4*)(b + l*4);
    bf16 o[4];
    o[0] = f2b((v.x-mean)*rs*gg.x + bb.x);
    o[1] = f2b((v.y-mean)*rs*gg.y + bb.y);
    o[2] = f2b((v.z-mean)*rs*gg.z + bb.z);
    o[3] = f2b((v.w-mean)*rs*gg.w + bb.w);
    *(uint2*)(out + (size_t)t*CC + l*4) = *(uint2*)o;
}

// ---------------- MFMA GEMM: A[M,K]bf16 @ Bt[N,K]bf16 + bias fp32 --------------
// tile TMx128, BK=64, 4 waves; XOR-swizzled LDS chunks. Compile-time K,N,TM.
// EPI: 0 = bf16; 2 = gelu->bf16; 3 = +resid(fp32)->fp32;
//      4 = col<256 -> val_t[n][h][lq][32] bf16 (gather-optimal), else bf16 vc
template<int EPI, int K, int N, int TM>
__global__ __launch_bounds__(256) void mfma_gemm(const bf16* __restrict__ A,
                                                 const bf16* __restrict__ Bt,
                                                 const float* __restrict__ bias,
                                                 void* __restrict__ outv,
                                                 const float* __restrict__ resid,
                                                 bf16* __restrict__ val_t)
{
    constexpr int AR  = TM/8;        // A regions (8 rows each)
    constexpr int TR  = AR + 16;     // + B regions (128 rows)
    constexpr int RPW = TR/4;        // regions staged per wave
    constexpr int NJ  = (TM==128) ? 4 : 2;
    __shared__ short As[TM*64];
    __shared__ short Bs[128*64];
    const int tid = threadIdx.x;
    const int w = tid >> 6, l = tid & 63;
    const int bm = blockIdx.x, bn = blockIdx.y;

    const bf16* sbase[RPW];
    short*      lbase[RPW];
    {
        const int lrow = l >> 3;
        const int q    = (l & 7) ^ lrow;
        #pragma unroll
        for (int j = 0; j < RPW; j++) {
            int r = w*RPW + j;
            bool isA = r < AR;
            int rr = isA ? r : r - AR;
            int row = rr*8 + lrow;
            size_t grow = (size_t)(isA ? (bm*TM + row) : (bn*128 + row));
            sbase[j] = (isA ? A : Bt) + grow*K + q*8;
            lbase[j] = (isA ? As : Bs) + rr*512;
        }
    }

    const int mbase = (TM==128) ? 64*(w >> 1) : 0;
    const int nbase = (TM==128) ? 64*(w & 1)  : 32*w;

    int aoff[2][4], boff[2][NJ];
    #pragma unroll
    for (int s = 0; s < 2; s++) {
        const int q = s*4 + (l >> 4);
        #pragma unroll
        for (int i = 0; i < 4; i++) {
            int m = mbase + i*16 + (l & 15);
            aoff[s][i] = (m*8 + (q ^ (m & 7))) * 8;
        }
        #pragma unroll
        for (int j = 0; j < NJ; j++) {
            int n = nbase + j*16 + (l & 15);
            boff[s][j] = (n*8 + (q ^ (n & 7))) * 8;
        }
    }

    f32x4 acc[4][NJ];
    #pragma unroll
    for (int i = 0; i < 4; i++)
        #pragma unroll
        for (int j = 0; j < NJ; j++)
            acc[i][j] = (f32x4){0.f, 0.f, 0.f, 0.f};

    for (int k0 = 0; k0 < K; k0 += 64) {
        #pragma unroll
        for (int j = 0; j < RPW; j++)
            gl2lds16(sbase[j] + k0, lbase[j]);
        __syncthreads();
        #pragma unroll
        for (int s = 0; s < 2; s++) {
            short8 af[4], bfr[NJ];
            #pragma unroll
            for (int i = 0; i < 4; i++)  af[i]  = *(const short8*)(As + aoff[s][i]);
            #pragma unroll
            for (int j = 0; j < NJ; j++) bfr[j] = *(const short8*)(Bs + boff[s][j]);
            #pragma unroll
            for (int i = 0; i < 4; i++)
                #pragma unroll
                for (int j = 0; j < NJ; j++)
                    acc[i][j] = __builtin_amdgcn_mfma_f32_16x16x32_bf16(af[i], bfr[j], acc[i][j], 0, 0, 0);
        }
        __syncthreads();
    }

    const int row0 = bm*TM + mbase + (l >> 4)*4;
    const int col0 = bn*128 + nbase + (l & 15);
    #pragma unroll
    for (int i = 0; i < 4; i++) {
        #pragma unroll
        for (int j = 0; j < NJ; j++) {
            const int col = col0 + j*16;
            const float bs = bias[col];
            #pragma unroll
            for (int r = 0; r < 4; r++) {
                const int row = row0 + i*16 + r;
                float v = acc[i][j][r] + bs;
                size_t o = (size_t)row * N + col;
                if (EPI == 0) {
                    ((bf16*)outv)[o] = f2b(v);
                } else if (EPI == 2) {
                    ((bf16*)outv)[o] = f2b(0.5f * v * (1.f + erff(v * 0.70710678118654752f)));
                } else if (EPI == 3) {
                    ((float*)outv)[o] = v + resid[o];
                } else { // 4: scatter val cols into [n][h][lq][32] layout
                    if (col < 256) {
                        const int n_  = (row >= LQ) ? 1 : 0;
                        const int lq_ = row - n_*LQ;
                        const int h_  = col >> 5, dh_ = col & 31;
                        val_t[((size_t)(n_*NHEADS + h_)*LQ + lq_)*DHH + dh_] = f2b(v);
                    } else {
                        ((bf16*)outv)[o] = f2b(v);
                    }
                }
            }
        }
    }
}

// ---------------- Deformable sampling, phase-split, fused softmax ---------------
// Phase 1: 64 (t,h) pairs x 4 threads: softmax (quad shuffle) + 16B Tap records.
// Phase 2: lane = (token, head, channel-oct); per tap one 16B bf16 gather where
// 4 octs of a (t,h) consume one full 64B line of val_t[n][h][pix][32].
struct __align__(16) Tap { _Float16 w[4]; unsigned short i[4]; };

__global__ __launch_bounds__(256) void sample_kernel(const bf16* __restrict__ vc,
                                                     const bf16* __restrict__ val_t,
                                                     const float* __restrict__ refp,
                                                     bf16* __restrict__ samp)
{
    __shared__ Tap taps[TB*200];
    const int b = blockIdx.x;                        // 2304 blocks
    const int tbase = ((b & 7)*288 + (b >> 3)) * TB; // XCD range swizzle
    const int tid = threadIdx.x;

    // ---- phase 1
    {
        const int pair = tid >> 2;
        const int j    = tid & 3;
        const int tl   = pair >> 3;
        const int h    = pair & 7;
        const int t    = tbase + tl;
        const bf16* row = vc + (size_t)t*NVC;

        float lg[7];
        #pragma unroll
        for (int k = 0; k < 7; k++) {
            int p = j + 4*k;
            lg[k] = (p < PP) ? b2f(row[656 + h*25 + p]) : -1e30f;
        }
        float m = lg[0];
        #pragma unroll
        for (int k = 1; k < 7; k++) m = fmaxf(m, lg[k]);
        m = fmaxf(m, __shfl_xor(m, 1));
        m = fmaxf(m, __shfl_xor(m, 2));
        float s = 0.f;
        float ex[7];
        #pragma unroll
        for (int k = 0; k < 7; k++) {
            ex[k] = (j + 4*k < PP) ? expf(lg[k] - m) : 0.f;
            s += ex[k];
        }
        s += __shfl_xor(s, 1);
        s += __shfl_xor(s, 2);
        const float inv = 1.f / s;

        const float rx96 = refp[(size_t)t*2 + 0]*96.f - 0.5f;
        const float ry96 = refp[(size_t)t*2 + 1]*96.f - 0.5f;
        const unsigned* offp = (const unsigned*)(row + 256 + h*50);

        #pragma unroll
        for (int k = 0; k < 7; k++) {
            const int p = j + 4*k;
            if (p >= PP) break;
            const float a = ex[k] * inv;
            const unsigned uo = offp[p];
            const float gx = rx96 + lo_bf(uo);
            const float gy = ry96 + hi_bf(uo);
            const float x0f = floorf(gx), y0f = floorf(gy);
            const float fx = gx - x0f, fy = gy - y0f;
            const int ix = (int)x0f, iy = (int)y0f;
            Tap tp;
            #pragma unroll
            for (int d = 0; d < 4; d++) {
                const int dx = d & 1, dy = d >> 1;
                const int xi = ix + dx, yi = iy + dy;
                const bool valid = (xi >= 0) & (xi <= WW-1) & (yi >= 0) & (yi <= HH-1);
                const int xc = min(max(xi, 0), WW-1);
                const int yc = min(max(yi, 0), HH-1);
                tp.i[d] = (unsigned short)(yc*WW + xc);
                tp.w[d] = (_Float16)(valid ? a * (dx ? fx : 1.f-fx) * (dy ? fy : 1.f-fy) : 0.f);
            }
            taps[tl*200 + h*25 + p] = tp;
        }
    }
    __syncthreads();

    // ---- phase 2: line-aligned bf16 gathers
    const int wv_ = tid >> 6, l = tid & 63;
    const int tl  = wv_*2 + (l >> 5);
    const int r   = l & 31;
    const int h   = r >> 2, oct = r & 3;
    const int c0  = h*DHH + oct*8;
    const int t   = tbase + tl;
    const int n   = (t >= LQ) ? 1 : 0;
    const bf16* pv = val_t + (size_t)(n*NHEADS + h)*LQ*DHH + oct*8;
    const int pib = tl*200 + h*25;

    float acc[8] = {0.f,0.f,0.f,0.f,0.f,0.f,0.f,0.f};
    #pragma unroll 5
    for (int p = 0; p < PP; p++) {
        const uint4 tv = *((const uint4*)taps + (pib + p));
        const _Float16* wp_ = (const _Float16*)&tv;
        const unsigned short* ip_ = (const unsigned short*)&tv + 4;
        #pragma unroll
        for (int d = 0; d < 4; d++) {
            const float wt = (float)wp_[d];
            const uint4 vv = *(const uint4*)(pv + (size_t)ip_[d]*DHH);
            acc[0] += wt*lo_bf(vv.x); acc[1] += wt*hi_bf(vv.x);
            acc[2] += wt*lo_bf(vv.y); acc[3] += wt*hi_bf(vv.y);
            acc[4] += wt*lo_bf(vv.z); acc[5] += wt*hi_bf(vv.z);
            acc[6] += wt*lo_bf(vv.w); acc[7] += wt*hi_bf(vv.w);
        }
    }
    bf16 o[8];
    #pragma unroll
    for (int j2 = 0; j2 < 8; j2++) o[j2] = f2b(acc[j2]);
    *(uint4*)(samp + (size_t)t*CC + c0) = *(uint4*)o;
}

// ---------------- Launch ---------------------------------------------------------
extern "C" void kernel_launch(void* const* d_in, const int* in_sizes, int n_in,
                              void* d_out, int out_size, void* d_ws, size_t ws_size,
                              hipStream_t stream)
{
    const float* x      = (const float*)d_in[0];
    const float* refp   = (const float*)d_in[1];
    const float* ln1_g  = (const float*)d_in[4];
    const float* ln1_b  = (const float*)d_in[5];
    const float* w_off  = (const float*)d_in[6];
    const float* b_off  = (const float*)d_in[7];
    const float* w_attn = (const float*)d_in[8];
    const float* b_attn = (const float*)d_in[9];
    const float* w_val  = (const float*)d_in[10];
    const float* b_val  = (const float*)d_in[11];
    const float* w_out  = (const float*)d_in[12];
    const float* b_out  = (const float*)d_in[13];
    const float* ln2_g  = (const float*)d_in[14];
    const float* ln2_b  = (const float*)d_in[15];
    const float* w_fc1  = (const float*)d_in[16];
    const float* b_fc1  = (const float*)d_in[17];
    const float* w_fc2  = (const float*)d_in[18];
    const float* b_fc2  = (const float*)d_in[19];

    // workspace layout
    char* wsb = (char*)d_ws;
    bf16*  q     = (bf16*)(wsb + 0);           //  9,437,184
    bf16*  vc    = (bf16*)(wsb + 9437184);     // 33,030,144 (TT*896 bf16)
    bf16*  samp  = (bf16*)(wsb + 42467328);    //  9,437,184
    float* x1    = (float*)(wsb + 51904512);   // 18,874,368
    bf16*  wvcT  = (bf16*)(wsb + 70778880);    //    458,752
    bf16*  wfc1T = (bf16*)(wsb + 71237632);    //    524,288
    bf16*  wfc2T = (bf16*)(wsb + 71761920);    //    524,288
    bf16*  woutT = (bf16*)(wsb + 72286208);    //    131,072
    float* bvc   = (float*)(wsb + 72417280);   //      3,584
    bf16*  val_t = (bf16*)(wsb + 72420864);    //  9,437,184 -> 81,858,048 total
    bf16*  hid   = (bf16*)(wsb + 0);           // overlays q+vc (42.5MB >= 37.7MB)
    bf16*  y0    = samp;                       // overlays samp after out-proj

    if (ws_size < 81858048) return;

    const dim3 blk(256);
    // 0. weight prep
    prep_all<<<dim3(3200), blk, 0, stream>>>(w_val, w_off, w_attn, w_fc1, w_fc2, w_out,
                                             b_val, b_off, b_attn,
                                             wvcT, wfc1T, wfc2T, woutT, bvc);
    // 1. LN1
    ln_kernel<<<dim3(TT/4), blk, 0, stream>>>(x, ln1_g, ln1_b, q);
    // 2. fused value|off|attn GEMM -> val_t (bf16, gather layout) + vc (bf16)
    mfma_gemm<4,256,NVC,128><<<dim3(TT/128, NVC/128), blk, 0, stream>>>(q, wvcT, bvc, (void*)vc, nullptr, val_t);
    // 3. deformable sampling (softmax fused)
    sample_kernel<<<dim3(TT/TB), blk, 0, stream>>>(vc, val_t, refp, samp);
    // 4. out-projection + residual -> x1 (fp32); TM=64 for 576 blocks
    mfma_gemm<3,256,CC,64><<<dim3(TT/64, CC/128), blk, 0, stream>>>(samp, woutT, b_out, (void*)x1, x, nullptr);
    // 5. LN2
    ln_kernel<<<dim3(TT/4), blk, 0, stream>>>(x1, ln2_g, ln2_b, y0);
    // 6. fc1 + gelu
    mfma_gemm<2,256,HIDN,128><<<dim3(TT/128, HIDN/128), blk, 0, stream>>>(y0, wfc1T, b_fc1, (void*)hid, nullptr, nullptr);
    // 7. fc2 + residual -> out (fp32); TM=64
    mfma_gemm<3,HIDN,CC,64><<<dim3(TT/64, CC/128), blk, 0, stream>>>(hid, wfc2T, b_fc2, d_out, x1, nullptr);
}

// Round 8
// 240.916 us; speedup vs baseline: 1.1467x; 1.1467x over previous
//
#include <hip/hip_runtime.h>
#include <hip/hip_bf16.h>
#include <math.h>

typedef __hip_bfloat16 bf16;
typedef __attribute__((ext_vector_type(8))) short short8;
typedef __attribute__((ext_vector_type(4))) float f32x4;

#define NB 2
#define HH 96
#define WW 96
#define CC 256
#define NHEADS 8
#define PP 25
#define DHH 32
#define HIDN 1024
#define LQ (HH*WW)          // 9216
#define TT (NB*LQ)          // 18432
#define NVC 896             // 256 val + 400 off + 200 attn + 40 pad
#define TB 8                // tokens per sample block

__device__ __forceinline__ float b2f(bf16 v){ return __bfloat162float(v); }
__device__ __forceinline__ bf16  f2b(float v){ return __float2bfloat16(v); }
__device__ __forceinline__ float lo_bf(unsigned u){ return __uint_as_float(u << 16); }
__device__ __forceinline__ float hi_bf(unsigned u){ return __uint_as_float(u & 0xffff0000u); }

__device__ __forceinline__ void gl2lds16(const void* g, void* l) {
    __builtin_amdgcn_global_load_lds(
        (const __attribute__((address_space(1))) unsigned int*)g,
        (__attribute__((address_space(3))) unsigned int*)l, 16, 0, 0);
}

// ---------------- all weight prep in one kernel ---------------------------------
__global__ __launch_bounds__(256) void prep_all(const float* __restrict__ w_val,
                                                const float* __restrict__ w_off,
                                                const float* __restrict__ w_attn,
                                                const float* __restrict__ w_fc1,
                                                const float* __restrict__ w_fc2,
                                                const float* __restrict__ w_out,
                                                const float* __restrict__ b_val,
                                                const float* __restrict__ b_off,
                                                const float* __restrict__ b_attn,
                                                bf16* __restrict__ wvcT,
                                                bf16* __restrict__ wfc1T,
                                                bf16* __restrict__ wfc2T,
                                                bf16* __restrict__ woutT,
                                                float* __restrict__ bvc)
{
    const int idx = blockIdx.x*256 + threadIdx.x;   // < 819200
    if (idx < 229376) {                              // wvcT [896][256]
        int n = idx >> 8, k = idx & 255;
        float v = (n < 256) ? w_val[(size_t)k*256 + n]
                : (n < 656) ? w_off[(size_t)k*400 + (n-256)]
                : (n < 856) ? w_attn[(size_t)k*200 + (n-656)] : 0.f;
        wvcT[idx] = f2b(v);
    } else if (idx < 491520) {                       // wfc1T [1024][256]
        int j = idx - 229376; int n = j >> 8, k = j & 255;
        wfc1T[j] = f2b(w_fc1[(size_t)k*1024 + n]);
    } else if (idx < 753664) {                       // wfc2T [256][1024]
        int j = idx - 491520; int n = j >> 10, k = j & 1023;
        wfc2T[j] = f2b(w_fc2[(size_t)k*256 + n]);
    } else if (idx < 819200) {                       // woutT [256][256]
        int j = idx - 753664; int n = j >> 8, k = j & 255;
        woutT[j] = f2b(w_out[(size_t)k*256 + n]);
    }
    if (idx < NVC)
        bvc[idx] = (idx < 256) ? b_val[idx]
                 : (idx < 656) ? b_off[idx-256]
                 : (idx < 856) ? b_attn[idx-656] : 0.f;
}

// ---------------- LayerNorm: one wave per token, 4 ch/lane ----------------------
__global__ __launch_bounds__(256) void ln_kernel(const float* __restrict__ x,
                                                 const float* __restrict__ g,
                                                 const float* __restrict__ b,
                                                 bf16* __restrict__ out)
{
    const int t = blockIdx.x*4 + (threadIdx.x >> 6);
    const int l = threadIdx.x & 63;
    const float4 v = *(const float4*)(x + (size_t)t*CC + l*4);
    float s  = v.x + v.y + v.z + v.w;
    float s2 = v.x*v.x + v.y*v.y + v.z*v.z + v.w*v.w;
    #pragma unroll
    for (int m = 1; m < 64; m <<= 1) { s += __shfl_xor(s, m); s2 += __shfl_xor(s2, m); }
    const float mean = s * (1.f/CC);
    const float var  = s2 * (1.f/CC) - mean*mean;
    const float rs   = 1.f / sqrtf(var + 1e-5f);
    const float4 gg = *(const float4*)(g + l*4);
    const float4 bb = *(const float4*)(b + l*4);
    bf16 o[4];
    o[0] = f2b((v.x-mean)*rs*gg.x + bb.x);
    o[1] = f2b((v.y-mean)*rs*gg.y + bb.y);
    o[2] = f2b((v.z-mean)*rs*gg.z + bb.z);
    o[3] = f2b((v.w-mean)*rs*gg.w + bb.w);
    *(uint2*)(out + (size_t)t*CC + l*4) = *(uint2*)o;
}

// ---------------- MFMA GEMM: A[M,K]bf16 @ Bt[N,K]bf16 + bias fp32 --------------
// tile TMx128, BK=64, 4 waves; XOR-swizzled LDS chunks. Compile-time K,N,TM.
// EPI: 0 = bf16; 2 = gelu->bf16; 3 = +resid(fp32)->fp32;
//      4 = col<256 -> dense bf16 val_d[row][col] (row stride 256), else bf16 vc
template<int EPI, int K, int N, int TM>
__global__ __launch_bounds__(256) void mfma_gemm(const bf16* __restrict__ A,
                                                 const bf16* __restrict__ Bt,
                                                 const float* __restrict__ bias,
                                                 void* __restrict__ outv,
                                                 const float* __restrict__ resid,
                                                 bf16* __restrict__ val_d)
{
    constexpr int AR  = TM/8;        // A regions (8 rows each)
    constexpr int TR  = AR + 16;     // + B regions (128 rows)
    constexpr int RPW = TR/4;        // regions staged per wave
    constexpr int NJ  = (TM==128) ? 4 : 2;
    __shared__ short As[TM*64];
    __shared__ short Bs[128*64];
    const int tid = threadIdx.x;
    const int w = tid >> 6, l = tid & 63;
    const int bm = blockIdx.x, bn = blockIdx.y;

    const bf16* sbase[RPW];
    short*      lbase[RPW];
    {
        const int lrow = l >> 3;
        const int q    = (l & 7) ^ lrow;
        #pragma unroll
        for (int j = 0; j < RPW; j++) {
            int r = w*RPW + j;
            bool isA = r < AR;
            int rr = isA ? r : r - AR;
            int row = rr*8 + lrow;
            size_t grow = (size_t)(isA ? (bm*TM + row) : (bn*128 + row));
            sbase[j] = (isA ? A : Bt) + grow*K + q*8;
            lbase[j] = (isA ? As : Bs) + rr*512;
        }
    }

    const int mbase = (TM==128) ? 64*(w >> 1) : 0;
    const int nbase = (TM==128) ? 64*(w & 1)  : 32*w;

    int aoff[2][4], boff[2][NJ];
    #pragma unroll
    for (int s = 0; s < 2; s++) {
        const int q = s*4 + (l >> 4);
        #pragma unroll
        for (int i = 0; i < 4; i++) {
            int m = mbase + i*16 + (l & 15);
            aoff[s][i] = (m*8 + (q ^ (m & 7))) * 8;
        }
        #pragma unroll
        for (int j = 0; j < NJ; j++) {
            int n = nbase + j*16 + (l & 15);
            boff[s][j] = (n*8 + (q ^ (n & 7))) * 8;
        }
    }

    f32x4 acc[4][NJ];
    #pragma unroll
    for (int i = 0; i < 4; i++)
        #pragma unroll
        for (int j = 0; j < NJ; j++)
            acc[i][j] = (f32x4){0.f, 0.f, 0.f, 0.f};

    for (int k0 = 0; k0 < K; k0 += 64) {
        #pragma unroll
        for (int j = 0; j < RPW; j++)
            gl2lds16(sbase[j] + k0, lbase[j]);
        __syncthreads();
        #pragma unroll
        for (int s = 0; s < 2; s++) {
            short8 af[4], bfr[NJ];
            #pragma unroll
            for (int i = 0; i < 4; i++)  af[i]  = *(const short8*)(As + aoff[s][i]);
            #pragma unroll
            for (int j = 0; j < NJ; j++) bfr[j] = *(const short8*)(Bs + boff[s][j]);
            #pragma unroll
            for (int i = 0; i < 4; i++)
                #pragma unroll
                for (int j = 0; j < NJ; j++)
                    acc[i][j] = __builtin_amdgcn_mfma_f32_16x16x32_bf16(af[i], bfr[j], acc[i][j], 0, 0, 0);
        }
        __syncthreads();
    }

    const int row0 = bm*TM + mbase + (l >> 4)*4;
    const int col0 = bn*128 + nbase + (l & 15);
    #pragma unroll
    for (int i = 0; i < 4; i++) {
        #pragma unroll
        for (int j = 0; j < NJ; j++) {
            const int col = col0 + j*16;
            const float bs = bias[col];
            #pragma unroll
            for (int r = 0; r < 4; r++) {
                const int row = row0 + i*16 + r;
                float v = acc[i][j][r] + bs;
                size_t o = (size_t)row * N + col;
                if (EPI == 0) {
                    ((bf16*)outv)[o] = f2b(v);
                } else if (EPI == 2) {
                    ((bf16*)outv)[o] = f2b(0.5f * v * (1.f + erff(v * 0.70710678118654752f)));
                } else if (EPI == 3) {
                    ((float*)outv)[o] = v + resid[o];
                } else { // 4: val cols -> dense [row][256] buffer; rest -> vc
                    if (col < 256) val_d[(size_t)row*CC + col] = f2b(v);
                    else           ((bf16*)outv)[o] = f2b(v);
                }
            }
        }
    }
}

// ---------------- Deformable sampling, phase-split, fused softmax ---------------
// Phase 1: 64 (t,h) pairs x 4 threads: softmax (quad shuffle) + 16B Tap records.
// Phase 2: lane = (token, head, channel-oct); 16B bf16 gathers from dense
// val_d[n][pixel][256] rows (8 heads of a token touch one 512B blob).
// Batch-aware XCD swizzle: XCDs 0-3 -> batch 0, XCDs 4-7 -> batch 1
// (per-XCD gather working set 4.7MB ~= one XCD L2).
struct __align__(16) Tap { _Float16 w[4]; unsigned short i[4]; };

__global__ __launch_bounds__(256) void sample_kernel(const bf16* __restrict__ vc,
                                                     const bf16* __restrict__ val_d,
                                                     const float* __restrict__ refp,
                                                     bf16* __restrict__ samp)
{
    __shared__ Tap taps[TB*200];
    const int b = blockIdx.x;                        // 2304 blocks
    const int xcd  = b & 7, sub = b >> 3;            // 288 subs per xcd
    const int tbase = (xcd >> 2)*LQ + ((xcd & 3)*288 + sub)*TB;
    const int tid = threadIdx.x;

    // ---- phase 1
    {
        const int pair = tid >> 2;
        const int j    = tid & 3;
        const int tl   = pair >> 3;
        const int h    = pair & 7;
        const int t    = tbase + tl;
        const bf16* row = vc + (size_t)t*NVC;

        float lg[7];
        #pragma unroll
        for (int k = 0; k < 7; k++) {
            int p = j + 4*k;
            lg[k] = (p < PP) ? b2f(row[656 + h*25 + p]) : -1e30f;
        }
        float m = lg[0];
        #pragma unroll
        for (int k = 1; k < 7; k++) m = fmaxf(m, lg[k]);
        m = fmaxf(m, __shfl_xor(m, 1));
        m = fmaxf(m, __shfl_xor(m, 2));
        float s = 0.f;
        float ex[7];
        #pragma unroll
        for (int k = 0; k < 7; k++) {
            ex[k] = (j + 4*k < PP) ? expf(lg[k] - m) : 0.f;
            s += ex[k];
        }
        s += __shfl_xor(s, 1);
        s += __shfl_xor(s, 2);
        const float inv = 1.f / s;

        const float rx96 = refp[(size_t)t*2 + 0]*96.f - 0.5f;
        const float ry96 = refp[(size_t)t*2 + 1]*96.f - 0.5f;
        const unsigned* offp = (const unsigned*)(row + 256 + h*50);

        #pragma unroll
        for (int k = 0; k < 7; k++) {
            const int p = j + 4*k;
            if (p >= PP) break;
            const float a = ex[k] * inv;
            const unsigned uo = offp[p];
            const float gx = rx96 + lo_bf(uo);
            const float gy = ry96 + hi_bf(uo);
            const float x0f = floorf(gx), y0f = floorf(gy);
            const float fx = gx - x0f, fy = gy - y0f;
            const int ix = (int)x0f, iy = (int)y0f;
            Tap tp;
            #pragma unroll
            for (int d = 0; d < 4; d++) {
                const int dx = d & 1, dy = d >> 1;
                const int xi = ix + dx, yi = iy + dy;
                const bool valid = (xi >= 0) & (xi <= WW-1) & (yi >= 0) & (yi <= HH-1);
                const int xc = min(max(xi, 0), WW-1);
                const int yc = min(max(yi, 0), HH-1);
                tp.i[d] = (unsigned short)(yc*WW + xc);
                tp.w[d] = (_Float16)(valid ? a * (dx ? fx : 1.f-fx) * (dy ? fy : 1.f-fy) : 0.f);
            }
            taps[tl*200 + h*25 + p] = tp;
        }
    }
    __syncthreads();

    // ---- phase 2: 16B gathers from dense 512B pixel rows
    const int wv_ = tid >> 6, l = tid & 63;
    const int tl  = wv_*2 + (l >> 5);
    const int r   = l & 31;
    const int h   = r >> 2, oct = r & 3;
    const int c0  = h*DHH + oct*8;
    const int t   = tbase + tl;
    const int n   = (t >= LQ) ? 1 : 0;
    const bf16* pv = val_d + (size_t)n*LQ*CC + c0;
    const int pib = tl*200 + h*25;

    float acc[8] = {0.f,0.f,0.f,0.f,0.f,0.f,0.f,0.f};
    for (int p = 0; p < PP; p++) {
        const uint4 tv = *((const uint4*)taps + (pib + p));
        const _Float16* wp_ = (const _Float16*)&tv;
        const unsigned short* ip_ = (const unsigned short*)&tv + 4;
        #pragma unroll
        for (int d = 0; d < 4; d++) {
            const float wt = (float)wp_[d];
            const uint4 vv = *(const uint4*)(pv + (size_t)ip_[d]*CC);
            acc[0] += wt*lo_bf(vv.x); acc[1] += wt*hi_bf(vv.x);
            acc[2] += wt*lo_bf(vv.y); acc[3] += wt*hi_bf(vv.y);
            acc[4] += wt*lo_bf(vv.z); acc[5] += wt*hi_bf(vv.z);
            acc[6] += wt*lo_bf(vv.w); acc[7] += wt*hi_bf(vv.w);
        }
    }
    bf16 o[8];
    #pragma unroll
    for (int j2 = 0; j2 < 8; j2++) o[j2] = f2b(acc[j2]);
    *(uint4*)(samp + (size_t)t*CC + c0) = *(uint4*)o;
}

// ---------------- Launch ---------------------------------------------------------
extern "C" void kernel_launch(void* const* d_in, const int* in_sizes, int n_in,
                              void* d_out, int out_size, void* d_ws, size_t ws_size,
                              hipStream_t stream)
{
    const float* x      = (const float*)d_in[0];
    const float* refp   = (const float*)d_in[1];
    const float* ln1_g  = (const float*)d_in[4];
    const float* ln1_b  = (const float*)d_in[5];
    const float* w_off  = (const float*)d_in[6];
    const float* b_off  = (const float*)d_in[7];
    const float* w_attn = (const float*)d_in[8];
    const float* b_attn = (const float*)d_in[9];
    const float* w_val  = (const float*)d_in[10];
    const float* b_val  = (const float*)d_in[11];
    const float* w_out  = (const float*)d_in[12];
    const float* b_out  = (const float*)d_in[13];
    const float* ln2_g  = (const float*)d_in[14];
    const float* ln2_b  = (const float*)d_in[15];
    const float* w_fc1  = (const float*)d_in[16];
    const float* b_fc1  = (const float*)d_in[17];
    const float* w_fc2  = (const float*)d_in[18];
    const float* b_fc2  = (const float*)d_in[19];

    // workspace layout
    char* wsb = (char*)d_ws;
    bf16*  q     = (bf16*)(wsb + 0);           //  9,437,184
    bf16*  vc    = (bf16*)(wsb + 9437184);     // 33,030,144 (TT*896 bf16)
    bf16*  samp  = (bf16*)(wsb + 42467328);    //  9,437,184
    float* x1    = (float*)(wsb + 51904512);   // 18,874,368
    bf16*  wvcT  = (bf16*)(wsb + 70778880);    //    458,752
    bf16*  wfc1T = (bf16*)(wsb + 71237632);    //    524,288
    bf16*  wfc2T = (bf16*)(wsb + 71761920);    //    524,288
    bf16*  woutT = (bf16*)(wsb + 72286208);    //    131,072
    float* bvc   = (float*)(wsb + 72417280);   //      3,584
    bf16*  val_d = (bf16*)(wsb + 72420864);    //  9,437,184 -> 81,858,048 total
    bf16*  hid   = (bf16*)(wsb + 0);           // overlays q+vc (42.5MB >= 37.7MB)
    bf16*  y0    = samp;                       // overlays samp after out-proj

    if (ws_size < 81858048) return;

    const dim3 blk(256);
    // 0. weight prep
    prep_all<<<dim3(3200), blk, 0, stream>>>(w_val, w_off, w_attn, w_fc1, w_fc2, w_out,
                                             b_val, b_off, b_attn,
                                             wvcT, wfc1T, wfc2T, woutT, bvc);
    // 1. LN1
    ln_kernel<<<dim3(TT/4), blk, 0, stream>>>(x, ln1_g, ln1_b, q);
    // 2. fused value|off|attn GEMM -> val_d (dense bf16) + vc (off/attn bf16)
    mfma_gemm<4,256,NVC,128><<<dim3(TT/128, NVC/128), blk, 0, stream>>>(q, wvcT, bvc, (void*)vc, nullptr, val_d);
    // 3. deformable sampling (softmax fused)
    sample_kernel<<<dim3(TT/TB), blk, 0, stream>>>(vc, val_d, refp, samp);
    // 4. out-projection + residual -> x1 (fp32); TM=64 for 576 blocks
    mfma_gemm<3,256,CC,64><<<dim3(TT/64, CC/128), blk, 0, stream>>>(samp, woutT, b_out, (void*)x1, x, nullptr);
    // 5. LN2
    ln_kernel<<<dim3(TT/4), blk, 0, stream>>>(x1, ln2_g, ln2_b, y0);
    // 6. fc1 + gelu
    mfma_gemm<2,256,HIDN,128><<<dim3(TT/128, HIDN/128), blk, 0, stream>>>(y0, wfc1T, b_fc1, (void*)hid, nullptr, nullptr);
    // 7. fc2 + residual -> out (fp32); TM=64
    mfma_gemm<3,HIDN,CC,64><<<dim3(TT/64, CC/128), blk, 0, stream>>>(hid, wfc2T, b_fc2, d_out, x1, nullptr);
}